// Round 7
// baseline (228.610 us; speedup 1.0000x reference)
//
#include <hip/hip_runtime.h>
#include <math.h>

// Z = Q_F (D * (Q_F^T X Q_S)) Q_S^T  ==  per-column solve (I - g*lam_j*G) y_j = (X Q_S)_j ; Z = Y Q_S^T
// (I - aG)^-1 = prod_{j=0..4} (I + a^(2^j) G^(2^j))  (exact 31-term Neumann sum; rho <= 0.76)
// GEMMs: bf16 MFMA, A = hi+lo split (2 products), B = bf16 (2^-9 rel, OK vs 0.099 threshold).
//
// R7: R6 evidence: 160.5 us with ALL four kernels <= 40.6 us -> kernel bodies, not only
// gaps, fill the budget; KSPLIT=32 doubled slab streaming (128 MB) and cancelled its
// parallelism gain. Changes:
//  1. KSPLIT back to 16; gemm1 reverted to the R2-proven body (depth-2 B prefetch,
//     KCHUNK=256, nodrain barriers).
//  2. reduce2 fused into gemm2 as a WAIT-FREE split-K finisher: store slab ->
//     syncthreads (drain) -> threadfence (release) -> per-n-tile device fetch_add;
//     the 16th arriver re-reads the 16 slabs for its tile (256 KB) and writes Z.
//     No spin anywhere (vs R4's spinning grid barrier); 64 ctr x 16 increments only.
//  Dispatches: gemm1(+prep) -> solve -> gemm2(+finish).  Ctr zeroed via 256 B memsetAsync.

typedef short short8 __attribute__((ext_vector_type(8)));
typedef float floatx16 __attribute__((ext_vector_type(16)));

#define KSPLIT 16
#define KCHUNK 256  // 4096 / KSPLIT, 4 steps of 64
constexpr int Mdim = 64;
constexpr int Ndim = 4096;
constexpr int TILE = Mdim * Ndim;  // 262144 floats = 1 MB

__device__ inline ushort f2bf(float f) {
    uint u = __float_as_uint(f);
    u += 0x7fff + ((u >> 16) & 1);  // RNE
    return (ushort)(u >> 16);
}
__device__ inline float bf2f(ushort h) { return __uint_as_float(((uint)h) << 16); }

__device__ inline floatx16 mfma_bf16(short8 a, short8 b, floatx16 c) {
    return __builtin_amdgcn_mfma_f32_32x32x16_bf16(a, b, c, 0, 0, 0);
}

// LDS plane layout (bf16, 64x64 tile): elem (r,k) at r*64 + ((k>>3)^(r&7))*8 + (k&7).
union SharedG1 {
    struct { ushort Ah[4096], Al[4096], Bh[4096]; } g;     // gemm1 (24 KB)
    struct { ushort planes[2][4096]; float red[256]; } p;  // prep (17 KB)
};

// Workgroup barrier WITHOUT vmcnt drain: LDS visibility only needs lgkmcnt(0).
__device__ inline void barrier_nodrain() {
    asm volatile("s_waitcnt lgkmcnt(0)" ::: "memory");
    __builtin_amdgcn_s_barrier();
    __builtin_amdgcn_sched_barrier(0);
}

// ---------------- prep body: G, G^2, G^4, G^8, G^16 (one block) -------------
__device__ void prep_body(SharedG1& sh, const float* __restrict__ F, float* __restrict__ Gout) {
    const int t = threadIdx.x;
    const int l = t & 63, w = t >> 6;
    const int tm = w & 1, tn = w >> 1;
    const int am = tm * 32 + (l & 31);
    const int bn = tn * 32 + (l & 31);
    const int lk = l >> 5;
    ushort* Ph = sh.p.planes[0];
    ushort* Pl = sh.p.planes[1];
    float* red = sh.p.red;

    {  // load F rows from global, scatter transposed into planes: P[c][k] = F[k][c]
        const int r = t >> 2, c0 = (t & 3) * 16;
#pragma unroll
        for (int q = 0; q < 4; ++q) {
            float4 v = *(const float4*)&F[r * 64 + c0 + 4 * q];
            float fa[4] = {v.x, v.y, v.z, v.w};
#pragma unroll
            for (int i = 0; i < 4; ++i) {
                int c = c0 + 4 * q + i;
                ushort h = f2bf(fa[i]);
                int idx = c * 64 + (((r >> 3) ^ (c & 7)) * 8) + (r & 7);
                Ph[idx] = h;
                Pl[idx] = f2bf(fa[i] - bf2f(h));
            }
        }
    }
    barrier_nodrain();
    floatx16 acc;
    for (int i = 0; i < 16; ++i) acc[i] = 0.f;
    for (int s16 = 0; s16 < 4; ++s16) {
        int gk = 2 * s16 + lk;
        int ai = am * 64 + ((gk ^ (am & 7)) * 8);
        int bi = bn * 64 + ((gk ^ (bn & 7)) * 8);
        short8 ah = *(const short8*)&Ph[ai];
        short8 al = *(const short8*)&Pl[ai];
        short8 bh = *(const short8*)&Ph[bi];
        short8 bl = *(const short8*)&Pl[bi];
        acc = mfma_bf16(ah, bh, acc);
        acc = mfma_bf16(al, bh, acc);
        acc = mfma_bf16(ah, bl, acc);
    }
    float ss = 0.f;
    for (int r = 0; r < 16; ++r) ss += acc[r] * acc[r];
    red[t] = ss;
    barrier_nodrain();
    for (int off = 128; off > 0; off >>= 1) {
        if (t < off) red[t] += red[t + off];
        barrier_nodrain();
    }
    const float inv = 1.0f / (sqrtf(red[0]) + 1e-12f);
    for (int r = 0; r < 16; ++r) {
        int row = (r & 3) + 8 * (r >> 2) + 4 * lk + tm * 32;
        int col = tn * 32 + (l & 31);
        float v = acc[r] * inv;
        Gout[row * 64 + col] = v;
        ushort h = f2bf(v);
        int idx = row * 64 + (((col >> 3) ^ (row & 7)) * 8 + (col & 7));
        Ph[idx] = h;
        Pl[idx] = f2bf(v - bf2f(h));
    }
    for (int j = 1; j < 5; ++j) {
        barrier_nodrain();
        floatx16 a2;
        for (int i = 0; i < 16; ++i) a2[i] = 0.f;
        for (int s16 = 0; s16 < 4; ++s16) {
            int gk = 2 * s16 + lk;
            int ai = am * 64 + ((gk ^ (am & 7)) * 8);
            int bi = bn * 64 + ((gk ^ (bn & 7)) * 8);
            short8 ah = *(const short8*)&Ph[ai];
            short8 al = *(const short8*)&Pl[ai];
            short8 bh = *(const short8*)&Ph[bi];
            short8 bl = *(const short8*)&Pl[bi];
            a2 = mfma_bf16(ah, bh, a2);
            a2 = mfma_bf16(al, bh, a2);
            a2 = mfma_bf16(ah, bl, a2);
        }
        barrier_nodrain();
        for (int r = 0; r < 16; ++r) {
            int row = (r & 3) + 8 * (r >> 2) + 4 * lk + tm * 32;
            int col = tn * 32 + (l & 31);
            float v = a2[r];
            Gout[j * 4096 + row * 64 + col] = v;
            ushort h = f2bf(v);
            int idx = row * 64 + (((col >> 3) ^ (row & 7)) * 8 + (col & 7));
            Ph[idx] = h;
            Pl[idx] = f2bf(v - bf2f(h));
        }
    }
}

// B-panel register load for one 64-k step.
template <bool TB>
__device__ inline void load_b(float4 (&dst)[4], const float* __restrict__ Bm,
                              int n0, int kk, int sr, int sj, int nq, int kr2) {
    if constexpr (TB) {
#pragma unroll
        for (int s = 0; s < 4; ++s)
            dst[s] = *(const float4*)&Bm[(size_t)(n0 + sr) * 4096 + kk + 4 * sj + 16 * s];
    } else {
#pragma unroll
        for (int s = 0; s < 2; ++s) {
            dst[2 * s + 0] = *(const float4*)&Bm[(size_t)(kk + kr2 + 32 * s) * 4096 + n0 + 4 * nq];
            dst[2 * s + 1] = *(const float4*)&Bm[(size_t)(kk + kr2 + 1 + 32 * s) * 4096 + n0 + 4 * nq];
        }
    }
}

// ---------------- gemm1: P1[ks] tile = X-chunk @ Qs-chunk (+ prep, block 0) -
// R2-proven body: depth-2 B register prefetch, A (L2-hot) in-step, hi+lo A split,
// nodrain barriers, slab stores.
__global__ __launch_bounds__(256, 4) void gemm1_kernel(const float* __restrict__ A,
                                                       const float* __restrict__ Bm,
                                                       float* __restrict__ C,
                                                       const float* __restrict__ F,
                                                       float* __restrict__ Gp) {
    __shared__ SharedG1 sh;
    const int bid = blockIdx.x;
    if (bid == 0) { prep_body(sh, F, Gp); return; }
    const int b = bid - 1;
    const int n0 = (b & 63) * 64;
    const int ks = b >> 6;
    const int kb = ks * KCHUNK;
    const int t = threadIdx.x;
    const int l = t & 63, w = t >> 6;
    const int tm = w & 1, tn = w >> 1;
    const int am = tm * 32 + (l & 31);
    const int bn = tn * 32 + (l & 31);
    const int lk = l >> 5;
    const int sr = t >> 2, sj = t & 3;          // row-staging map
    const int nq = t & 15, kr2 = 2 * (t >> 4);  // transpose-staging map

    floatx16 acc;
    for (int i = 0; i < 16; ++i) acc[i] = 0.f;

    float4 bbuf[4][4];
    load_b<false>(bbuf[0], Bm, n0, kb, sr, sj, nq, kr2);
    load_b<false>(bbuf[1], Bm, n0, kb + 64, sr, sj, nq, kr2);

#pragma unroll
    for (int step = 0; step < KCHUNK / 64; ++step) {
        const int k0 = kb + step * 64;
        // A loads for this step (L2-hot, short latency)
        float4 av[4];
#pragma unroll
        for (int s = 0; s < 4; ++s)
            av[s] = *(const float4*)&A[sr * 4096 + k0 + 4 * sj + 16 * s];
        // prefetch B two steps ahead (HBM latency spans ~2 steps of staging+MFMA)
        if (step + 2 < KCHUNK / 64)
            load_b<false>(bbuf[step + 2], Bm, n0, k0 + 128, sr, sj, nq, kr2);
        barrier_nodrain();  // previous step's frag ds_reads done (lgkm only; vmem in flight)
        // stage B (hi only); counted vmcnt inserted at first bbuf[step] use
#pragma unroll
        for (int s = 0; s < 2; ++s) {
            int k = kr2 + 32 * s;
            float fa[4] = {bbuf[step][2 * s].x, bbuf[step][2 * s].y, bbuf[step][2 * s].z, bbuf[step][2 * s].w};
            float fb[4] = {bbuf[step][2 * s + 1].x, bbuf[step][2 * s + 1].y, bbuf[step][2 * s + 1].z, bbuf[step][2 * s + 1].w};
#pragma unroll
            for (int i = 0; i < 4; ++i) {
                int n = 4 * nq + i;
                int idx = n * 64 + (((k >> 3) ^ (n & 7)) * 8 + (k & 7));
                ushort2 hp2;
                hp2.x = f2bf(fa[i]);
                hp2.y = f2bf(fb[i]);
                *(ushort2*)&sh.g.Bh[idx] = hp2;
            }
        }
        // stage A (hi + lo)
#pragma unroll
        for (int s = 0; s < 4; ++s) {
            int off = 4 * sj + 16 * s;
            int idx = sr * 64 + (((off >> 3) ^ (sr & 7)) * 8 + (off & 7));
            float fa[4] = {av[s].x, av[s].y, av[s].z, av[s].w};
            ushort4 h4, l4;
            ushort* hp = (ushort*)&h4; ushort* lp = (ushort*)&l4;
#pragma unroll
            for (int i = 0; i < 4; ++i) {
                ushort h = f2bf(fa[i]);
                hp[i] = h; lp[i] = f2bf(fa[i] - bf2f(h));
            }
            *(ushort4*)&sh.g.Ah[idx] = h4;
            *(ushort4*)&sh.g.Al[idx] = l4;
        }
        barrier_nodrain();  // staged planes visible to all waves
#pragma unroll
        for (int s16 = 0; s16 < 4; ++s16) {
            int gk = 2 * s16 + lk;
            int ai = am * 64 + ((gk ^ (am & 7)) * 8);
            int bi = bn * 64 + ((gk ^ (bn & 7)) * 8);
            short8 ah = *(const short8*)&sh.g.Ah[ai];
            short8 al = *(const short8*)&sh.g.Al[ai];
            short8 bh = *(const short8*)&sh.g.Bh[bi];
            acc = mfma_bf16(ah, bh, acc);
            acc = mfma_bf16(al, bh, acc);
        }
    }
    float* Cp = C + (size_t)ks * TILE;
    const int colg = n0 + tn * 32 + (l & 31);
#pragma unroll
    for (int r = 0; r < 16; ++r) {
        int row = (r & 3) + 8 * (r >> 2) + 4 * lk + tm * 32;
        Cp[row * 4096 + colg] = acc[r];
    }
}

// ---------------- solve: T = sum slabs; Neumann; emit Ybf hi/lo planes ------
// 256 blocks x 16 columns. Slab-reduce fused (reads P1 directly).
// Epilogue writes Y as bf16 hi/lo planes in MFMA-fragment layout [R4-verified]:
// elem (r, col) at (col>>3)*512 + r*8 + (col&7).
__global__ __launch_bounds__(256) void solve_kernel(const float* __restrict__ P1,
                                                    const float* __restrict__ Gp,
                                                    const float* __restrict__ lam,
                                                    const float* __restrict__ gammap,
                                                    ushort* __restrict__ Yh,
                                                    ushort* __restrict__ Yl) {
    __shared__ float Gs[64][68];
    __shared__ float T[64][17];
    const int t = threadIdx.x;
    const int c0 = blockIdx.x * 16;
    {  // fused slab reduction: thread (r, q) sums KSPLIT slabs for cols 4q..4q+3
        const int r = t >> 2, q = t & 3;
        float4 a = {0.f, 0.f, 0.f, 0.f};
        for (int s = 0; s < KSPLIT; ++s) {
            const float4 v = *(const float4*)&P1[(size_t)s * TILE + (size_t)r * 4096 + c0 + 4 * q];
            a.x += v.x; a.y += v.y; a.z += v.z; a.w += v.w;
        }
        T[r][4 * q + 0] = a.x;
        T[r][4 * q + 1] = a.y;
        T[r][4 * q + 2] = a.z;
        T[r][4 * q + 3] = a.w;
    }
    const int tx = t & 15;
    const int r4 = (t >> 4) * 4;
    const float a0 = gammap[0] * lam[c0 + tx];
    float s = a0;
    for (int j = 0; j < 5; ++j) {
        __syncthreads();
        for (int e = t; e < 4096; e += 256) Gs[e >> 6][e & 63] = Gp[j * 4096 + e];
        __syncthreads();
        float u0 = 0.f, u1 = 0.f, u2 = 0.f, u3 = 0.f;
#pragma unroll 8
        for (int k = 0; k < 64; ++k) {
            const float tv = T[k][tx];
            const float4 g = *(const float4*)&Gs[k][r4];
            u0 += g.x * tv; u1 += g.y * tv; u2 += g.z * tv; u3 += g.w * tv;
        }
        __syncthreads();
        T[r4 + 0][tx] += s * u0;
        T[r4 + 1][tx] += s * u1;
        T[r4 + 2][tx] += s * u2;
        T[r4 + 3][tx] += s * u3;
        s = s * s;
    }
    __syncthreads();
    for (int e = t; e < 1024; e += 256) {
        const int r = e >> 4, cc = e & 15, col = c0 + cc;
        const float v = T[r][cc];
        const ushort h = f2bf(v);
        const int idx = (col >> 3) * 512 + r * 8 + (col & 7);
        Yh[idx] = h;
        Yl[idx] = f2bf(v - bf2f(h));
    }
}

// ---------------- gemm2 + finisher: Z tile = sum_ks (Ybf @ Qs^T) ------------
// A-frags register-direct from Ybf planes; LDS = B dbuf only (16 KB); ring-3 B
// prefetch; ONE nodrain barrier/step [R4-verified]. Wait-free split-K finish:
// the 16th block per n-tile re-reads the 16 slabs and writes Z.
__global__ __launch_bounds__(256, 4) void gemm2_kernel(const ushort* __restrict__ Yh,
                                                       const ushort* __restrict__ Yl,
                                                       const float* __restrict__ Bm,
                                                       float* __restrict__ P2,
                                                       float* __restrict__ Z,
                                                       uint* __restrict__ cnt) {
    __shared__ ushort Bhs[2][4096];
    __shared__ uint sOld;
    const int b = blockIdx.x;
    const int nt = b & 63;
    const int n0 = nt * 64;
    const int ks = b >> 6;
    const int kb = ks * KCHUNK;
    const int t = threadIdx.x;
    const int l = t & 63, w = t >> 6;
    const int tm = w & 1, tn = w >> 1;
    const int am = tm * 32 + (l & 31);
    const int bn = tn * 32 + (l & 31);
    const int lk = l >> 5;
    const int sr = t >> 2, sj = t & 3;  // row-staging map (TB=true)

    floatx16 acc;
    for (int i = 0; i < 16; ++i) acc[i] = 0.f;

    float4 bbuf[3][4];
    load_b<true>(bbuf[0], Bm, n0, kb, sr, sj, 0, 0);
    load_b<true>(bbuf[1], Bm, n0, kb + 64, sr, sj, 0, 0);

#pragma unroll
    for (int step = 0; step < KCHUNK / 64; ++step) {
        const int k0 = kb + step * 64;
        const int par = step & 1;
        const int slot = step % 3;
        // prefetch B two steps ahead into free ring slot
        if (step + 2 < KCHUNK / 64)
            load_b<true>(bbuf[(step + 2) % 3], Bm, n0, k0 + 128, sr, sj, 0, 0);
        // A frags direct from Ybf planes (L2/L3-hot, 16B coalesced)
        short8 afh[4], afl[4];
#pragma unroll
        for (int s16 = 0; s16 < 4; ++s16) {
            int gk = (k0 >> 3) + 2 * s16 + lk;
            afh[s16] = *(const short8*)&Yh[gk * 512 + am * 8];
            afl[s16] = *(const short8*)&Yl[gk * 512 + am * 8];
        }
        // stage B (hi only) into dbuf half; counted vmcnt at first bbuf[slot] use
#pragma unroll
        for (int s = 0; s < 4; ++s) {
            int off = 4 * sj + 16 * s;
            int idx = sr * 64 + (((off >> 3) ^ (sr & 7)) * 8 + (off & 7));
            float fb[4] = {bbuf[slot][s].x, bbuf[slot][s].y, bbuf[slot][s].z, bbuf[slot][s].w};
            ushort4 h4;
            ushort* hp = (ushort*)&h4;
#pragma unroll
            for (int i = 0; i < 4; ++i) hp[i] = f2bf(fb[i]);
            *(ushort4*)&Bhs[par][idx] = h4;
        }
        barrier_nodrain();  // this half's writes visible; prev-half reads drained (lgkm)
#pragma unroll
        for (int s16 = 0; s16 < 4; ++s16) {
            int gk = 2 * s16 + lk;
            int bi = bn * 64 + ((gk ^ (bn & 7)) * 8);
            short8 bh = *(const short8*)&Bhs[par][bi];
            acc = mfma_bf16(afh[s16], bh, acc);
            acc = mfma_bf16(afl[s16], bh, acc);
        }
    }
    // store this block's slab tile
    float* Cp = P2 + (size_t)ks * TILE;
    const int colg = n0 + tn * 32 + (l & 31);
#pragma unroll
    for (int r = 0; r < 16; ++r) {
        int row = (r & 3) + 8 * (r >> 2) + 4 * lk + tm * 32;
        Cp[row * 4096 + colg] = acc[r];
    }
    // ---- wait-free split-K finish: last arriver per n-tile sums the slabs ----
    __syncthreads();      // drains vmcnt(0): all slab stores acked into L2
    if (t == 0) {
        __threadfence();  // release: slab visible device-wide
        sOld = __hip_atomic_fetch_add(&cnt[nt], 1u, __ATOMIC_ACQ_REL, __HIP_MEMORY_SCOPE_AGENT);
    }
    __syncthreads();
    if (sOld == KSPLIT - 1) {
        __threadfence();  // acquire: see all 16 slabs
        for (int e = t; e < 1024; e += 256) {
            const int r = e >> 4, cq = e & 15;
            const size_t off = (size_t)r * 4096 + n0 + 4 * cq;
            float4 a = {0.f, 0.f, 0.f, 0.f};
#pragma unroll
            for (int s = 0; s < KSPLIT; ++s) {
                const float4 v = *(const float4*)&P2[(size_t)s * TILE + off];
                a.x += v.x; a.y += v.y; a.z += v.z; a.w += v.w;
            }
            *(float4*)&Z[off] = a;
        }
    }
}

extern "C" void kernel_launch(void* const* d_in, const int* in_sizes, int n_in,
                              void* d_out, int out_size, void* d_ws, size_t ws_size,
                              hipStream_t stream) {
    const float* X     = (const float*)d_in[0];
    const float* F     = (const float*)d_in[1];
    const float* Qs    = (const float*)d_in[2];
    const float* lam   = (const float*)d_in[3];
    const float* gamma = (const float*)d_in[4];
    float* Z = (float*)d_out;

    float* P1 = (float*)d_ws;                    // 16 MB partial slabs (gemm1)
    float* P2 = P1 + (size_t)KSPLIT * TILE;      // 16 MB partial slabs (gemm2)
    float* Gp = P2 + (size_t)KSPLIT * TILE;      // 80 KB: G, G^2, G^4, G^8, G^16
    ushort* Yh = (ushort*)(Gp + 5 * 4096);       // 512 KB Y hi plane (fragment layout)
    ushort* Yl = Yh + TILE;                      // 512 KB Y lo plane
    uint* cnt  = (uint*)(Yl + TILE);             // 64 per-n-tile finish counters

    hipMemsetAsync(cnt, 0, 256, stream);         // zero counters (every replay)
    gemm1_kernel<<<64 * KSPLIT + 1, 256, 0, stream>>>(X, Qs, P1, F, Gp);
    solve_kernel<<<Ndim / 16, 256, 0, stream>>>(P1, Gp, lam, gamma, Yh, Yl);
    gemm2_kernel<<<64 * KSPLIT, 256, 0, stream>>>(Yh, Yl, Qs, P2, Z, cnt);
}

// Round 8
// 158.481 us; speedup vs baseline: 1.4425x; 1.4425x over previous
//
#include <hip/hip_runtime.h>
#include <math.h>

// Z = Q_F (D * (Q_F^T X Q_S)) Q_S^T  ==  per-column solve (I - g*lam_j*G) y_j = (X Q_S)_j ; Z = Y Q_S^T
// (I - aG)^-1 = prod_{j=0..4} (I + a^(2^j) G^(2^j))  (exact 31-term Neumann sum; rho <= 0.76)
// GEMMs: bf16 MFMA, A = hi+lo split (2 products), B = bf16 (2^-9 rel, OK vs 0.099 threshold).
//
// R8: R7 evidence: per-block __threadfence (L2 writeback) x1024 made gemm2 92 us -> no
// device-scope fences anywhere. R2/R6 comparison: fusing slab-reduce into solve swapped a
// coalesced read for a strided gather -> keep reduce separate. All slow paths share one
// signature: short bursts at 16-KB stride (B reads, C stores); contiguous paths run 4-6.5 TB/s.
// Changes vs R2 (155 us):
//  1. Slab stores TILE-CONTIGUOUS in fragment order (16 KB/block, fully coalesced);
//     reduce1 unchanged (elementwise); solve + reduce2z use the inverse index map
//     r=(row&3)|(((row>>3)&3)<<2), l=(col&31)+32*((row>>2)&1), w=(row>>5)+2*(col>>5).
//  2. gemm2-direct: A-frags register-direct from Ybf planes (R4/R6-verified), LDS = B dbuf.
//  3. solve reads W (1 MB gather, L2-hot), emits Ybf hi/lo planes (verified layout).
// Dispatches: gemm1(+prep) -> reduce1 -> solve -> gemm2 -> reduce2z.  No atomics, no memset.

typedef short short8 __attribute__((ext_vector_type(8)));
typedef float floatx16 __attribute__((ext_vector_type(16)));

#define KSPLIT 16
#define KCHUNK 256  // 4096 / KSPLIT, 4 steps of 64
constexpr int Mdim = 64;
constexpr int Ndim = 4096;
constexpr int TILE = Mdim * Ndim;  // 262144 floats = 1 MB

__device__ inline ushort f2bf(float f) {
    uint u = __float_as_uint(f);
    u += 0x7fff + ((u >> 16) & 1);  // RNE
    return (ushort)(u >> 16);
}
__device__ inline float bf2f(ushort h) { return __uint_as_float(((uint)h) << 16); }

__device__ inline floatx16 mfma_bf16(short8 a, short8 b, floatx16 c) {
    return __builtin_amdgcn_mfma_f32_32x32x16_bf16(a, b, c, 0, 0, 0);
}

// LDS plane layout (bf16, 64x64 tile): elem (r,k) at r*64 + ((k>>3)^(r&7))*8 + (k&7).
union SharedG1 {
    struct { ushort Ah[4096], Al[4096], Bh[4096]; } g;     // gemm1 (24 KB)
    struct { ushort planes[2][4096]; float red[256]; } p;  // prep (17 KB)
};

// Workgroup barrier WITHOUT vmcnt drain: LDS visibility only needs lgkmcnt(0).
__device__ inline void barrier_nodrain() {
    asm volatile("s_waitcnt lgkmcnt(0)" ::: "memory");
    __builtin_amdgcn_s_barrier();
    __builtin_amdgcn_sched_barrier(0);
}

// ---------------- prep body: G, G^2, G^4, G^8, G^16 (one block) -------------
__device__ void prep_body(SharedG1& sh, const float* __restrict__ F, float* __restrict__ Gout) {
    const int t = threadIdx.x;
    const int l = t & 63, w = t >> 6;
    const int tm = w & 1, tn = w >> 1;
    const int am = tm * 32 + (l & 31);
    const int bn = tn * 32 + (l & 31);
    const int lk = l >> 5;
    ushort* Ph = sh.p.planes[0];
    ushort* Pl = sh.p.planes[1];
    float* red = sh.p.red;

    {  // load F rows from global, scatter transposed into planes: P[c][k] = F[k][c]
        const int r = t >> 2, c0 = (t & 3) * 16;
#pragma unroll
        for (int q = 0; q < 4; ++q) {
            float4 v = *(const float4*)&F[r * 64 + c0 + 4 * q];
            float fa[4] = {v.x, v.y, v.z, v.w};
#pragma unroll
            for (int i = 0; i < 4; ++i) {
                int c = c0 + 4 * q + i;
                ushort h = f2bf(fa[i]);
                int idx = c * 64 + (((r >> 3) ^ (c & 7)) * 8) + (r & 7);
                Ph[idx] = h;
                Pl[idx] = f2bf(fa[i] - bf2f(h));
            }
        }
    }
    barrier_nodrain();
    floatx16 acc;
    for (int i = 0; i < 16; ++i) acc[i] = 0.f;
    for (int s16 = 0; s16 < 4; ++s16) {
        int gk = 2 * s16 + lk;
        int ai = am * 64 + ((gk ^ (am & 7)) * 8);
        int bi = bn * 64 + ((gk ^ (bn & 7)) * 8);
        short8 ah = *(const short8*)&Ph[ai];
        short8 al = *(const short8*)&Pl[ai];
        short8 bh = *(const short8*)&Ph[bi];
        short8 bl = *(const short8*)&Pl[bi];
        acc = mfma_bf16(ah, bh, acc);
        acc = mfma_bf16(al, bh, acc);
        acc = mfma_bf16(ah, bl, acc);
    }
    float ss = 0.f;
    for (int r = 0; r < 16; ++r) ss += acc[r] * acc[r];
    red[t] = ss;
    barrier_nodrain();
    for (int off = 128; off > 0; off >>= 1) {
        if (t < off) red[t] += red[t + off];
        barrier_nodrain();
    }
    const float inv = 1.0f / (sqrtf(red[0]) + 1e-12f);
    for (int r = 0; r < 16; ++r) {
        int row = (r & 3) + 8 * (r >> 2) + 4 * lk + tm * 32;
        int col = tn * 32 + (l & 31);
        float v = acc[r] * inv;
        Gout[row * 64 + col] = v;
        ushort h = f2bf(v);
        int idx = row * 64 + (((col >> 3) ^ (row & 7)) * 8 + (col & 7));
        Ph[idx] = h;
        Pl[idx] = f2bf(v - bf2f(h));
    }
    for (int j = 1; j < 5; ++j) {
        barrier_nodrain();
        floatx16 a2;
        for (int i = 0; i < 16; ++i) a2[i] = 0.f;
        for (int s16 = 0; s16 < 4; ++s16) {
            int gk = 2 * s16 + lk;
            int ai = am * 64 + ((gk ^ (am & 7)) * 8);
            int bi = bn * 64 + ((gk ^ (bn & 7)) * 8);
            short8 ah = *(const short8*)&Ph[ai];
            short8 al = *(const short8*)&Pl[ai];
            short8 bh = *(const short8*)&Ph[bi];
            short8 bl = *(const short8*)&Pl[bi];
            a2 = mfma_bf16(ah, bh, a2);
            a2 = mfma_bf16(al, bh, a2);
            a2 = mfma_bf16(ah, bl, a2);
        }
        barrier_nodrain();
        for (int r = 0; r < 16; ++r) {
            int row = (r & 3) + 8 * (r >> 2) + 4 * lk + tm * 32;
            int col = tn * 32 + (l & 31);
            float v = a2[r];
            Gout[j * 4096 + row * 64 + col] = v;
            ushort h = f2bf(v);
            int idx = row * 64 + (((col >> 3) ^ (row & 7)) * 8 + (col & 7));
            Ph[idx] = h;
            Pl[idx] = f2bf(v - bf2f(h));
        }
    }
}

// B-panel register load for one 64-k step.
template <bool TB>
__device__ inline void load_b(float4 (&dst)[4], const float* __restrict__ Bm,
                              int n0, int kk, int sr, int sj, int nq, int kr2) {
    if constexpr (TB) {
#pragma unroll
        for (int s = 0; s < 4; ++s)
            dst[s] = *(const float4*)&Bm[(size_t)(n0 + sr) * 4096 + kk + 4 * sj + 16 * s];
    } else {
#pragma unroll
        for (int s = 0; s < 2; ++s) {
            dst[2 * s + 0] = *(const float4*)&Bm[(size_t)(kk + kr2 + 32 * s) * 4096 + n0 + 4 * nq];
            dst[2 * s + 1] = *(const float4*)&Bm[(size_t)(kk + kr2 + 1 + 32 * s) * 4096 + n0 + 4 * nq];
        }
    }
}

// ---------------- gemm1: P1[ks] tile(nt) = X-chunk @ Qs-chunk (+ prep) ------
// R2-proven pipeline: depth-2 B register prefetch, A (L2-hot) in-step, hi+lo A,
// nodrain barriers. NEW: tile-contiguous fragment-order store (16 KB/block).
__global__ __launch_bounds__(256, 4) void gemm1_kernel(const float* __restrict__ A,
                                                       const float* __restrict__ Bm,
                                                       float* __restrict__ C,
                                                       const float* __restrict__ F,
                                                       float* __restrict__ Gp) {
    __shared__ SharedG1 sh;
    const int bid = blockIdx.x;
    if (bid == 0) { prep_body(sh, F, Gp); return; }
    const int b = bid - 1;
    const int nt = b & 63;
    const int n0 = nt * 64;
    const int ks = b >> 6;
    const int kb = ks * KCHUNK;
    const int t = threadIdx.x;
    const int l = t & 63, w = t >> 6;
    const int tm = w & 1, tn = w >> 1;
    const int am = tm * 32 + (l & 31);
    const int bn = tn * 32 + (l & 31);
    const int lk = l >> 5;
    const int sr = t >> 2, sj = t & 3;          // row-staging map
    const int nq = t & 15, kr2 = 2 * (t >> 4);  // transpose-staging map

    floatx16 acc;
    for (int i = 0; i < 16; ++i) acc[i] = 0.f;

    float4 bbuf[4][4];
    load_b<false>(bbuf[0], Bm, n0, kb, sr, sj, nq, kr2);
    load_b<false>(bbuf[1], Bm, n0, kb + 64, sr, sj, nq, kr2);

#pragma unroll
    for (int step = 0; step < KCHUNK / 64; ++step) {
        const int k0 = kb + step * 64;
        // A loads for this step (L2-hot, short latency)
        float4 av[4];
#pragma unroll
        for (int s = 0; s < 4; ++s)
            av[s] = *(const float4*)&A[sr * 4096 + k0 + 4 * sj + 16 * s];
        // prefetch B two steps ahead (HBM latency spans ~2 steps of staging+MFMA)
        if (step + 2 < KCHUNK / 64)
            load_b<false>(bbuf[step + 2], Bm, n0, k0 + 128, sr, sj, nq, kr2);
        barrier_nodrain();  // previous step's frag ds_reads done (lgkm only; vmem in flight)
        // stage B (hi only); counted vmcnt inserted at first bbuf[step] use
#pragma unroll
        for (int s = 0; s < 2; ++s) {
            int k = kr2 + 32 * s;
            float fa[4] = {bbuf[step][2 * s].x, bbuf[step][2 * s].y, bbuf[step][2 * s].z, bbuf[step][2 * s].w};
            float fb[4] = {bbuf[step][2 * s + 1].x, bbuf[step][2 * s + 1].y, bbuf[step][2 * s + 1].z, bbuf[step][2 * s + 1].w};
#pragma unroll
            for (int i = 0; i < 4; ++i) {
                int n = 4 * nq + i;
                int idx = n * 64 + (((k >> 3) ^ (n & 7)) * 8 + (k & 7));
                ushort2 hp2;
                hp2.x = f2bf(fa[i]);
                hp2.y = f2bf(fb[i]);
                *(ushort2*)&sh.g.Bh[idx] = hp2;
            }
        }
        // stage A (hi + lo)
#pragma unroll
        for (int s = 0; s < 4; ++s) {
            int off = 4 * sj + 16 * s;
            int idx = sr * 64 + (((off >> 3) ^ (sr & 7)) * 8 + (off & 7));
            float fa[4] = {av[s].x, av[s].y, av[s].z, av[s].w};
            ushort4 h4, l4;
            ushort* hp = (ushort*)&h4; ushort* lp = (ushort*)&l4;
#pragma unroll
            for (int i = 0; i < 4; ++i) {
                ushort h = f2bf(fa[i]);
                hp[i] = h; lp[i] = f2bf(fa[i] - bf2f(h));
            }
            *(ushort4*)&sh.g.Ah[idx] = h4;
            *(ushort4*)&sh.g.Al[idx] = l4;
        }
        barrier_nodrain();  // staged planes visible to all waves
#pragma unroll
        for (int s16 = 0; s16 < 4; ++s16) {
            int gk = 2 * s16 + lk;
            int ai = am * 64 + ((gk ^ (am & 7)) * 8);
            int bi = bn * 64 + ((gk ^ (bn & 7)) * 8);
            short8 ah = *(const short8*)&sh.g.Ah[ai];
            short8 al = *(const short8*)&sh.g.Al[ai];
            short8 bh = *(const short8*)&sh.g.Bh[bi];
            acc = mfma_bf16(ah, bh, acc);
            acc = mfma_bf16(al, bh, acc);
        }
    }
    // tile-contiguous fragment-order store: float idx = w*1024 + r*64 + l
    float* Cp = C + (size_t)ks * TILE + nt * 4096;
    const int base = w * 1024 + l;
#pragma unroll
    for (int r = 0; r < 16; ++r) Cp[base + r * 64] = acc[r];
}

// ---------------- reduce1: W = sum of KSPLIT P1 slabs (flat, coalesced) -----
__global__ __launch_bounds__(256) void reduce_kernel(const float* __restrict__ P,
                                                     float* __restrict__ out) {
    const int i = blockIdx.x * 256 + threadIdx.x;  // float4 index, 65536 total
    float4 a = {0.f, 0.f, 0.f, 0.f};
#pragma unroll
    for (int s = 0; s < KSPLIT; ++s) {
        const float4 v = *(const float4*)&P[(size_t)s * TILE + 4 * i];
        a.x += v.x; a.y += v.y; a.z += v.z; a.w += v.w;
    }
    *(float4*)&out[4 * i] = a;
}

// ---------------- solve: T from W (tile-order gather); Neumann; emit Ybf ----
// 256 blocks x 16 columns. W is 1 MB L2/L3-hot -> gather is cheap.
// Ybf layout [R4-verified]: elem (r, col) at (col>>3)*512 + r*8 + (col&7).
__global__ __launch_bounds__(256) void solve_kernel(const float* __restrict__ W,
                                                    const float* __restrict__ Gp,
                                                    const float* __restrict__ lam,
                                                    const float* __restrict__ gammap,
                                                    ushort* __restrict__ Yh,
                                                    ushort* __restrict__ Yl) {
    __shared__ float Gs[64][68];
    __shared__ float T[64][17];
    const int t = threadIdx.x;
    const int c0 = blockIdx.x * 16;
    const int nt = blockIdx.x >> 2;
    for (int e = t; e < 1024; e += 256) {
        const int row = e >> 4, cc = e & 15;
        const int cit = (blockIdx.x & 3) * 16 + cc;  // col within tile
        const int rr = (row & 3) | (((row >> 3) & 3) << 2);
        const int lk = (row >> 2) & 1;
        const int ww = (row >> 5) + 2 * (cit >> 5);
        const int ll = (cit & 31) + 32 * lk;
        T[row][cc] = W[nt * 4096 + ww * 1024 + rr * 64 + ll];
    }
    const int tx = t & 15;
    const int r4 = (t >> 4) * 4;
    const float a0 = gammap[0] * lam[c0 + tx];
    float s = a0;
    for (int j = 0; j < 5; ++j) {
        __syncthreads();
        for (int e = t; e < 4096; e += 256) Gs[e >> 6][e & 63] = Gp[j * 4096 + e];
        __syncthreads();
        float u0 = 0.f, u1 = 0.f, u2 = 0.f, u3 = 0.f;
#pragma unroll 8
        for (int k = 0; k < 64; ++k) {
            const float tv = T[k][tx];
            const float4 g = *(const float4*)&Gs[k][r4];
            u0 += g.x * tv; u1 += g.y * tv; u2 += g.z * tv; u3 += g.w * tv;
        }
        __syncthreads();
        T[r4 + 0][tx] += s * u0;
        T[r4 + 1][tx] += s * u1;
        T[r4 + 2][tx] += s * u2;
        T[r4 + 3][tx] += s * u3;
        s = s * s;
    }
    __syncthreads();
    for (int e = t; e < 1024; e += 256) {
        const int r = e >> 4, cc = e & 15, col = c0 + cc;
        const float v = T[r][cc];
        const ushort h = f2bf(v);
        const int idx = (col >> 3) * 512 + r * 8 + (col & 7);
        Yh[idx] = h;
        Yl[idx] = f2bf(v - bf2f(h));
    }
}

// ---------------- gemm2: P2[ks] tile(nt) = Ybf-chunk @ Qs^T-chunk -----------
// A-frags register-direct from Ybf planes (R4/R6-verified); LDS = B dbuf only
// (16 KB); depth-2 B prefetch; ONE nodrain barrier/step; tile-contiguous store.
__global__ __launch_bounds__(256, 4) void gemm2_kernel(const ushort* __restrict__ Yh,
                                                       const ushort* __restrict__ Yl,
                                                       const float* __restrict__ Bm,
                                                       float* __restrict__ C) {
    __shared__ ushort Bhs[2][4096];
    const int b = blockIdx.x;
    const int nt = b & 63;
    const int n0 = nt * 64;
    const int ks = b >> 6;
    const int kb = ks * KCHUNK;
    const int t = threadIdx.x;
    const int l = t & 63, w = t >> 6;
    const int tm = w & 1, tn = w >> 1;
    const int am = tm * 32 + (l & 31);
    const int bn = tn * 32 + (l & 31);
    const int lk = l >> 5;
    const int sr = t >> 2, sj = t & 3;  // row-staging map (TB=true)

    floatx16 acc;
    for (int i = 0; i < 16; ++i) acc[i] = 0.f;

    float4 bbuf[4][4];
    load_b<true>(bbuf[0], Bm, n0, kb, sr, sj, 0, 0);
    load_b<true>(bbuf[1], Bm, n0, kb + 64, sr, sj, 0, 0);

#pragma unroll
    for (int step = 0; step < KCHUNK / 64; ++step) {
        const int k0 = kb + step * 64;
        const int par = step & 1;
        // prefetch B two steps ahead
        if (step + 2 < KCHUNK / 64)
            load_b<true>(bbuf[step + 2], Bm, n0, k0 + 128, sr, sj, 0, 0);
        // A frags direct from Ybf planes (L2/L3-hot, 16B coalesced)
        short8 afh[4], afl[4];
#pragma unroll
        for (int s16 = 0; s16 < 4; ++s16) {
            int gk = (k0 >> 3) + 2 * s16 + lk;
            afh[s16] = *(const short8*)&Yh[gk * 512 + am * 8];
            afl[s16] = *(const short8*)&Yl[gk * 512 + am * 8];
        }
        // stage B (hi only) into dbuf half; counted vmcnt at first bbuf[step] use
#pragma unroll
        for (int s = 0; s < 4; ++s) {
            int off = 4 * sj + 16 * s;
            int idx = sr * 64 + (((off >> 3) ^ (sr & 7)) * 8 + (off & 7));
            float fb[4] = {bbuf[step][s].x, bbuf[step][s].y, bbuf[step][s].z, bbuf[step][s].w};
            ushort4 h4;
            ushort* hp = (ushort*)&h4;
#pragma unroll
            for (int i = 0; i < 4; ++i) hp[i] = f2bf(fb[i]);
            *(ushort4*)&Bhs[par][idx] = h4;
        }
        barrier_nodrain();  // this half's writes visible; prev-half reads drained (lgkm)
#pragma unroll
        for (int s16 = 0; s16 < 4; ++s16) {
            int gk = 2 * s16 + lk;
            int bi = bn * 64 + ((gk ^ (bn & 7)) * 8);
            short8 bh = *(const short8*)&Bhs[par][bi];
            acc = mfma_bf16(afh[s16], bh, acc);
            acc = mfma_bf16(afl[s16], bh, acc);
        }
    }
    // tile-contiguous fragment-order store
    float* Cp = C + (size_t)ks * TILE + nt * 4096;
    const int base = w * 1024 + l;
#pragma unroll
    for (int r = 0; r < 16; ++r) Cp[base + r * 64] = acc[r];
}

// ---------------- reduce2z: Z(row-major) = sum of P2 slabs (tile-order) -----
// 256 blocks: nt = bid&63, row-quarter q = bid>>6 (rows q*16..q*16+15).
// Quarter = {w = tm+2*tn, r in rbase..rbase+7, all l} with tm=q>>1, rbase=(q&1)*8.
__global__ __launch_bounds__(256) void reduce2z_kernel(const float* __restrict__ P,
                                                       float* __restrict__ Z) {
    __shared__ float a4[2][8][64];  // [tn][rr][l]
    const int bid = blockIdx.x;
    const int nt = bid & 63;
    const int q = bid >> 6;
    const int tm = q >> 1;
    const int rbase = (q & 1) * 8;
    const int t = threadIdx.x;
    // coalesced slab reads: thread (tn, rr, lq) sums 16 slabs for 4 floats
    const int tn = t >> 7, rr = (t >> 4) & 7, lq = t & 15;
    const size_t off = (size_t)nt * 4096 + (tm + 2 * tn) * 1024 + (rbase + rr) * 64 + 4 * lq;
    float4 a = {0.f, 0.f, 0.f, 0.f};
#pragma unroll
    for (int s = 0; s < KSPLIT; ++s) {
        const float4 v = *(const float4*)&P[(size_t)s * TILE + off];
        a.x += v.x; a.y += v.y; a.z += v.z; a.w += v.w;
    }
    *(float4*)&a4[tn][rr][4 * lq] = a;
    __syncthreads();
    // write row-major: thread -> (orow, 4-col quad)
    const int orow = q * 16 + (t >> 4);
    const int cquad = t & 15;
    const int lk = (orow >> 2) & 1;
    const int rr2 = ((orow & 3) | (((orow >> 3) & 3) << 2)) - rbase;  // in [0,8)
    float4 o;
    float* op = (float*)&o;
#pragma unroll
    for (int v = 0; v < 4; ++v) {
        const int col = 4 * cquad + v;
        op[v] = a4[col >> 5][rr2][(col & 31) + 32 * lk];
    }
    *(float4*)&Z[(size_t)orow * 4096 + nt * 64 + 4 * cquad] = o;
}

extern "C" void kernel_launch(void* const* d_in, const int* in_sizes, int n_in,
                              void* d_out, int out_size, void* d_ws, size_t ws_size,
                              hipStream_t stream) {
    const float* X     = (const float*)d_in[0];
    const float* F     = (const float*)d_in[1];
    const float* Qs    = (const float*)d_in[2];
    const float* lam   = (const float*)d_in[3];
    const float* gamma = (const float*)d_in[4];
    float* Z = (float*)d_out;

    float* P1 = (float*)d_ws;                    // 16 MB partial slabs (gemm1)
    float* P2 = P1 + (size_t)KSPLIT * TILE;      // 16 MB partial slabs (gemm2)
    float* W  = P2 + (size_t)KSPLIT * TILE;      // 1 MB reduced W (tile order)
    float* Gp = W + TILE;                        // 80 KB: G, G^2, G^4, G^8, G^16
    ushort* Yh = (ushort*)(Gp + 5 * 4096);       // 512 KB Y hi plane (fragment layout)
    ushort* Yl = Yh + TILE;                      // 512 KB Y lo plane

    gemm1_kernel<<<64 * KSPLIT + 1, 256, 0, stream>>>(X, Qs, P1, F, Gp);
    reduce_kernel<<<256, 256, 0, stream>>>(P1, W);
    solve_kernel<<<Ndim / 16, 256, 0, stream>>>(W, Gp, lam, gamma, Yh, Yl);
    gemm2_kernel<<<64 * KSPLIT, 256, 0, stream>>>(Yh, Yl, Qs, P2);
    reduce2z_kernel<<<256, 256, 0, stream>>>(P2, Z);
}